// Round 1
// baseline (1838.764 us; speedup 1.0000x reference)
//
#include <hip/hip_runtime.h>

// ============================================================================
// GQA prefill: B=4, S=2048, DIM=1152, NH=8, KVH=2, HD=144, causal, start_pos=0
//
// Pipeline:
//   1. cvt_f16: x, wq, wkv (concat, padded to 1792 rows), wo -> fp16 in ws
//   2. gemm_bt_f16: qkv = x @ [wq;wkv]^T + bias  (M=8192,N=1728,K=1152), fp32 out
//   3. rope_scatter: RoPE on q,k (fp32, exact); scatter to (b,h,s,d) layouts
//   4. attn_fp32: flash attention, TQ=64 TK=32, online softmax (fp32)
//   5. cvt_f16 + gemm_bt_f16: out = attn @ wo^T + bo -> d_out (fp32)
//
// ws layout (bytes, all 256-aligned), total ~139 MB:
//   x_f16/attn_f16 :        0 .. 18874368
//   wqkv_f16       : 18874368 .. 23003136   (1792x1152 fp16; rows 1728+ = pad)
//   wo_f16         : 23003136 .. 25657344
//   bias_qkv       : 25657344 .. 25664256
//   qkv/attn (f32) : 25664256 .. 82287360   (8192x1728; attn reuses as 8192x1152)
//   Qr             : 82287360 .. 120036096  (4,8,2048,144)
//   Kr             :120036096 .. 129473280  (4,2,2048,144)
//   Vr             :129473280 .. 138910464
// ============================================================================

#define THREADS 256

typedef _Float16 f16x8 __attribute__((ext_vector_type(8)));
typedef _Float16 f16x4 __attribute__((ext_vector_type(4)));
typedef float f32x4 __attribute__((ext_vector_type(4)));

// ---------------------------------------------------------------- cvt fp32->fp16
__global__ __launch_bounds__(THREADS) void cvt_f16(const float* __restrict__ in,
                                                   _Float16* __restrict__ out,
                                                   int n4) {
  int i = blockIdx.x * THREADS + threadIdx.x;
  if (i >= n4) return;
  float4 v = ((const float4*)in)[i];
  f16x4 o;
  o.x = (_Float16)v.x;
  o.y = (_Float16)v.y;
  o.z = (_Float16)v.z;
  o.w = (_Float16)v.w;
  ((f16x4*)out)[i] = o;
}

// ---------------------------------------------------------------- bias concat
__global__ __launch_bounds__(THREADS) void prep_bias(const float* __restrict__ bq,
                                                     const float* __restrict__ bkv,
                                                     float* __restrict__ bias) {
  int i = blockIdx.x * THREADS + threadIdx.x;
  if (i < 1152) bias[i] = bq[i];
  else if (i < 1728) bias[i] = bkv[i - 1152];
}

// ---------------------------------------------------------------- GEMM-BT fp16 MFMA
// C[m,n] = sum_k A[m,k]*B[n,k] + bias[n].  A: MxK fp16, B: NxK fp16, C: MxN fp32.
// 128x128 tile, BK=32, 4 waves each 64x64 via 4x4 grid of 16x16x32 MFMAs.
// Verified layouts (learn_hip m89/m91/m121): A/B frag: row=lane&15, k=quad*8+j;
// C/D: col=lane&15, row=quad*4+reg.
__global__ __launch_bounds__(THREADS) void gemm_bt_f16(
    const _Float16* __restrict__ A, const _Float16* __restrict__ B,
    const float* __restrict__ bias, float* __restrict__ C, int M, int N, int K) {
  __shared__ __align__(16) _Float16 As[128 * 32];
  __shared__ __align__(16) _Float16 Bs[128 * 32];
  const int t = threadIdx.x;
  const int m0 = blockIdx.y << 7, n0 = blockIdx.x << 7;
  const int w = t >> 6, lane = t & 63;
  const int wm = (w & 1) << 6, wn = (w >> 1) << 6;
  const int quad = lane >> 4, l16 = lane & 15;

  f32x4 acc[4][4] = {};

  for (int k0 = 0; k0 < K; k0 += 32) {
#pragma unroll
    for (int i = 0; i < 2; ++i) {
      const int c = t + (i << 8);           // chunk of 8 fp16 (16B)
      const int row = c >> 2, kc = (c & 3) << 3;
      float4 va = *(const float4*)(A + (size_t)(m0 + row) * K + (k0 + kc));
      float4 vb = *(const float4*)(B + (size_t)(n0 + row) * K + (k0 + kc));
      *(float4*)&As[c << 3] = va;
      *(float4*)&Bs[c << 3] = vb;
    }
    __syncthreads();
    f16x8 af[4], bf[4];
#pragma unroll
    for (int mi = 0; mi < 4; ++mi)
      af[mi] = *(const f16x8*)&As[((wm + (mi << 4) + l16) << 5) + (quad << 3)];
#pragma unroll
    for (int ni = 0; ni < 4; ++ni)
      bf[ni] = *(const f16x8*)&Bs[((wn + (ni << 4) + l16) << 5) + (quad << 3)];
#pragma unroll
    for (int mi = 0; mi < 4; ++mi)
#pragma unroll
      for (int ni = 0; ni < 4; ++ni)
        acc[mi][ni] =
            __builtin_amdgcn_mfma_f32_16x16x32_f16(af[mi], bf[ni], acc[mi][ni], 0, 0, 0);
    __syncthreads();
  }

#pragma unroll
  for (int mi = 0; mi < 4; ++mi) {
    const int row = m0 + wm + (mi << 4) + (quad << 2);
#pragma unroll
    for (int ni = 0; ni < 4; ++ni) {
      const int col = n0 + wn + (ni << 4) + l16;
      if (col < N) {
        const float bv = bias[col];
#pragma unroll
        for (int r = 0; r < 4; ++r)
          C[(size_t)(row + r) * N + col] = acc[mi][ni][r] + bv;
      }
    }
  }
}

// ---------------------------------------------------------------- RoPE + scatter
// qkv row (1728): [q 8x144 | k 2x144 | v 2x144]. Interleaved-pair RoPE on q,k.
// Outputs: Qr[b][h][s][144], Kr[b][kvh][s][144], Vr[b][kvh][s][144].
// One thread per float2 job: per row 576 q-pairs + 144 k-pairs + 144 v-copies = 864.
__global__ __launch_bounds__(THREADS) void rope_scatter(
    const float* __restrict__ qkv, const float* __restrict__ fc,
    const float* __restrict__ fs, float* __restrict__ Qr, float* __restrict__ Kr,
    float* __restrict__ Vr) {
  int idx = blockIdx.x * THREADS + threadIdx.x;
  int m = idx / 864;
  int c = idx - m * 864;
  int s = m & 2047, b = m >> 11;
  const float* row = qkv + (size_t)m * 1728;
  if (c < 720) {
    int h, d2;
    const float* src;
    float* dst;
    if (c < 576) {
      h = c / 72;
      d2 = c - h * 72;
      src = row + h * 144 + 2 * d2;
      dst = Qr + ((size_t)(b * 8 + h) * 2048 + s) * 144 + 2 * d2;
    } else {
      int cc = c - 576;
      h = cc / 72;
      d2 = cc - h * 72;
      src = row + 1152 + h * 144 + 2 * d2;
      dst = Kr + ((size_t)(b * 2 + h) * 2048 + s) * 144 + 2 * d2;
    }
    float2 v = *(const float2*)src;
    float cth = fc[s * 72 + d2], sth = fs[s * 72 + d2];
    float2 o;
    o.x = v.x * cth - v.y * sth;
    o.y = v.x * sth + v.y * cth;
    *(float2*)dst = o;
  } else {
    int cc = c - 720;
    int h = cc / 72, dd = cc - h * 72;
    *(float2*)(Vr + ((size_t)(b * 2 + h) * 2048 + s) * 144 + 2 * dd) =
        *(const float2*)(row + 1440 + h * 144 + 2 * dd);
  }
}

// ---------------------------------------------------------------- flash attention fp32
// Block = (qt, h, b): 64 queries, loop key tiles of 32. LDS: K/V tiles (stride 148
// to dodge bank conflicts), score tile Sc[64][36], online-softmax state.
// Q streamed from global (L1/L2-hot; 16 lanes share each address).
__global__ __launch_bounds__(THREADS) void attn_fp32(
    const float* __restrict__ Q, const float* __restrict__ Kc,
    const float* __restrict__ Vc, float* __restrict__ Out) {
  __shared__ __align__(16) float Ks[32 * 148];
  __shared__ __align__(16) float Vs[32 * 148];
  __shared__ float Sc[64 * 36];
  __shared__ float mRow[64], lRow[64], aRow[64];
  const int t = threadIdx.x;
  const int qt = blockIdx.x, h = blockIdx.y, b = blockIdx.z;
  const int kvh = h >> 2;  // GROUPS=4: q-head h uses kv-head h/4
  const float* Qg = Q + ((size_t)(b * 8 + h) * 2048 + qt * 64) * 144;
  const float* Kg = Kc + (size_t)(b * 2 + kvh) * 2048 * 144;
  const float* Vg = Vc + (size_t)(b * 2 + kvh) * 2048 * 144;
  const int rg2 = t >> 4, jg = t & 15;  // QK: rows rg2*4+i, keys jg, jg+16
  const int r_s = t >> 2, sub = t & 3;  // softmax: row r_s, 8 keys each
  const int rg = t & 15, dg = t >> 4;   // PV: rows rg+16i, dims dg*9..+8
  float O[4][9];
#pragma unroll
  for (int i = 0; i < 4; ++i)
#pragma unroll
    for (int dd = 0; dd < 9; ++dd) O[i][dd] = 0.f;
  if (t < 64) {
    mRow[t] = -INFINITY;
    lRow[t] = 0.f;
  }
  __syncthreads();
  const float scale = 0.08333333333333333f;  // 144^-0.5 = 1/12
  const int rbase = qt * 64 + rg2 * 4;       // abs qpos of this thread's row 0
  const float* qp0 = Qg + (rg2 * 4) * 144;
  const float* qp1 = qp0 + 144;
  const float* qp2 = qp0 + 288;
  const float* qp3 = qp0 + 432;
  const int nkt = 2 * qt + 2;  // key tiles of 32 covering kpos <= qt*64+63
  for (int kt = 0; kt < nkt; ++kt) {
    for (int idx = t; idx < 32 * 36; idx += THREADS) {
      int r = idx / 36, c4 = idx - r * 36;
      *(float4*)&Ks[r * 148 + c4 * 4] =
          *(const float4*)(Kg + (size_t)(kt * 32 + r) * 144 + c4 * 4);
      *(float4*)&Vs[r * 148 + c4 * 4] =
          *(const float4*)(Vg + (size_t)(kt * 32 + r) * 144 + c4 * 4);
    }
    __syncthreads();
    // ---- scores: 4 rows x 2 keys per thread
    float a00 = 0, a01 = 0, a10 = 0, a11 = 0, a20 = 0, a21 = 0, a30 = 0, a31 = 0;
    for (int d = 0; d < 144; d += 4) {
      float4 k0 = *(const float4*)&Ks[jg * 148 + d];
      float4 k1 = *(const float4*)&Ks[(jg + 16) * 148 + d];
      float4 qa = *(const float4*)(qp0 + d);
      float4 qb = *(const float4*)(qp1 + d);
      float4 qc = *(const float4*)(qp2 + d);
      float4 qd = *(const float4*)(qp3 + d);
      a00 += qa.x * k0.x + qa.y * k0.y + qa.z * k0.z + qa.w * k0.w;
      a01 += qa.x * k1.x + qa.y * k1.y + qa.z * k1.z + qa.w * k1.w;
      a10 += qb.x * k0.x + qb.y * k0.y + qb.z * k0.z + qb.w * k0.w;
      a11 += qb.x * k1.x + qb.y * k1.y + qb.z * k1.z + qb.w * k1.w;
      a20 += qc.x * k0.x + qc.y * k0.y + qc.z * k0.z + qc.w * k0.w;
      a21 += qc.x * k1.x + qc.y * k1.y + qc.z * k1.z + qc.w * k1.w;
      a30 += qd.x * k0.x + qd.y * k0.y + qd.z * k0.z + qd.w * k0.w;
      a31 += qd.x * k1.x + qd.y * k1.y + qd.z * k1.z + qd.w * k1.w;
    }
    {
      // causal mask: matches ref arithmetic exactly (s*scale - 1e9)
      const int j0 = kt * 32 + jg, j1 = j0 + 16;
      float s00 = a00 * scale, s01 = a01 * scale, s10 = a10 * scale, s11 = a11 * scale;
      float s20 = a20 * scale, s21 = a21 * scale, s30 = a30 * scale, s31 = a31 * scale;
      if (j0 > rbase + 0) s00 -= 1e9f;
      if (j1 > rbase + 0) s01 -= 1e9f;
      if (j0 > rbase + 1) s10 -= 1e9f;
      if (j1 > rbase + 1) s11 -= 1e9f;
      if (j0 > rbase + 2) s20 -= 1e9f;
      if (j1 > rbase + 2) s21 -= 1e9f;
      if (j0 > rbase + 3) s30 -= 1e9f;
      if (j1 > rbase + 3) s31 -= 1e9f;
      Sc[(rg2 * 4 + 0) * 36 + jg] = s00;
      Sc[(rg2 * 4 + 0) * 36 + jg + 16] = s01;
      Sc[(rg2 * 4 + 1) * 36 + jg] = s10;
      Sc[(rg2 * 4 + 1) * 36 + jg + 16] = s11;
      Sc[(rg2 * 4 + 2) * 36 + jg] = s20;
      Sc[(rg2 * 4 + 2) * 36 + jg + 16] = s21;
      Sc[(rg2 * 4 + 3) * 36 + jg] = s30;
      Sc[(rg2 * 4 + 3) * 36 + jg + 16] = s31;
    }
    __syncthreads();
    // ---- online softmax: 4 threads (consecutive lanes) per row, 8 keys each
    {
      float sv[8];
      float lm = -INFINITY;
#pragma unroll
      for (int qq = 0; qq < 8; ++qq) {
        sv[qq] = Sc[r_s * 36 + sub + 4 * qq];
        lm = fmaxf(lm, sv[qq]);
      }
      lm = fmaxf(lm, __shfl_xor(lm, 1, 64));
      lm = fmaxf(lm, __shfl_xor(lm, 2, 64));
      float mold = mRow[r_s];
      float mnew = fmaxf(mold, lm);
      float ls = 0.f;
#pragma unroll
      for (int qq = 0; qq < 8; ++qq) {
        float p = __expf(sv[qq] - mnew);
        Sc[r_s * 36 + sub + 4 * qq] = p;
        ls += p;
      }
      ls += __shfl_xor(ls, 1, 64);
      ls += __shfl_xor(ls, 2, 64);
      if (sub == 0) {
        float al = __expf(mold - mnew);
        aRow[r_s] = al;
        lRow[r_s] = lRow[r_s] * al + ls;
        mRow[r_s] = mnew;
      }
    }
    __syncthreads();
    // ---- O = O*alpha + P @ V
    {
      float al0 = aRow[rg], al1 = aRow[rg + 16], al2 = aRow[rg + 32],
            al3 = aRow[rg + 48];
#pragma unroll
      for (int dd = 0; dd < 9; ++dd) {
        O[0][dd] *= al0;
        O[1][dd] *= al1;
        O[2][dd] *= al2;
        O[3][dd] *= al3;
      }
#pragma unroll 4
      for (int j = 0; j < 32; ++j) {
        float p0 = Sc[rg * 36 + j];
        float p1 = Sc[(rg + 16) * 36 + j];
        float p2 = Sc[(rg + 32) * 36 + j];
        float p3 = Sc[(rg + 48) * 36 + j];
        const float* vrow = &Vs[j * 148 + dg * 9];
#pragma unroll
        for (int dd = 0; dd < 9; ++dd) {
          float v = vrow[dd];
          O[0][dd] += p0 * v;
          O[1][dd] += p1 * v;
          O[2][dd] += p2 * v;
          O[3][dd] += p3 * v;
        }
      }
    }
    __syncthreads();
  }
  // ---- epilogue: normalize and write (b, s, h*144+d)
#pragma unroll
  for (int i = 0; i < 4; ++i) {
    const int r = rg + 16 * i;
    const float inv = 1.f / lRow[r];
    float* orow = Out + ((size_t)b * 2048 + qt * 64 + r) * 1152 + h * 144 + dg * 9;
#pragma unroll
    for (int dd = 0; dd < 9; ++dd) orow[dd] = O[i][dd] * inv;
  }
}

// ============================================================================
extern "C" void kernel_launch(void* const* d_in, const int* in_sizes, int n_in,
                              void* d_out, int out_size, void* d_ws, size_t ws_size,
                              hipStream_t stream) {
  const float* x = (const float*)d_in[0];
  const float* wq = (const float*)d_in[1];
  const float* bq = (const float*)d_in[2];
  const float* wkv = (const float*)d_in[3];
  const float* bkv = (const float*)d_in[4];
  const float* wo = (const float*)d_in[5];
  const float* bo = (const float*)d_in[6];
  const float* fc = (const float*)d_in[7];
  const float* fs = (const float*)d_in[8];
  // d_in[9..12] (k_cache, v_cache, mask, start_pos) unused: start_pos=0 prefill
  // fully overwrites the cache window and the causal mask is replicated exactly.
  float* out = (float*)d_out;
  char* ws = (char*)d_ws;

  _Float16* x_f16 = (_Float16*)(ws + 0);
  _Float16* wqkv_f16 = (_Float16*)(ws + 18874368);
  _Float16* wo_f16 = (_Float16*)(ws + 23003136);
  float* bias_qkv = (float*)(ws + 25657344);
  float* qkv = (float*)(ws + 25664256);
  float* Qr = (float*)(ws + 82287360);
  float* Kr = (float*)(ws + 120036096);
  float* Vr = (float*)(ws + 129473280);
  float* attn = qkv;            // reuse: qkv dead after rope_scatter
  _Float16* attn_f16 = x_f16;   // reuse: x_f16 dead after qkv GEMM

  // 1. fp16 casts (weights concat: rows 0..1151 = wq, 1152..1727 = wkv)
  cvt_f16<<<9216, THREADS, 0, stream>>>(x, x_f16, 2359296);
  cvt_f16<<<1296, THREADS, 0, stream>>>(wq, wqkv_f16, 331776);
  cvt_f16<<<648, THREADS, 0, stream>>>(wkv, wqkv_f16 + 1327104, 165888);
  cvt_f16<<<1296, THREADS, 0, stream>>>(wo, wo_f16, 331776);
  prep_bias<<<7, THREADS, 0, stream>>>(bq, bkv, bias_qkv);
  // 2. fused QKV projection (N=1728 -> 14 col-tiles; B padded to 1792 rows)
  gemm_bt_f16<<<dim3(14, 64), THREADS, 0, stream>>>(x_f16, wqkv_f16, bias_qkv, qkv,
                                                    8192, 1728, 1152);
  // 3. RoPE + scatter to attention layouts
  rope_scatter<<<27648, THREADS, 0, stream>>>(qkv, fc, fs, Qr, Kr, Vr);
  // 4. flash attention
  attn_fp32<<<dim3(32, 8, 4), THREADS, 0, stream>>>(Qr, Kr, Vr, attn);
  // 5. output projection
  cvt_f16<<<9216, THREADS, 0, stream>>>(attn, attn_f16, 2359296);
  gemm_bt_f16<<<dim3(9, 64), THREADS, 0, stream>>>(attn_f16, wo_f16, bo, out, 8192,
                                                   1152, 1152);
}

// Round 2
// 565.112 us; speedup vs baseline: 3.2538x; 3.2538x over previous
//
#include <hip/hip_runtime.h>

// ============================================================================
// GQA prefill: B=4, S=2048, DIM=1152, NH=8, KVH=2, HD=144, causal, start_pos=0
//
// Pipeline:
//   1. cvt_f16: x, [wq;wkv] (1792-row padded), wo -> fp16
//   2. gemm_bt_f16: qkv = x @ [wq;wkv]^T + bias  (8192x1728, fp32)
//   3. rope_scatter_f16: RoPE (fp32 math) -> Qh/Kh fp16, d padded 144->160
//      v_transpose: V -> Vt fp16 [b][kvh][144][2048]   (PV needs B=[n=d][k=key])
//   4. attn_mfma: flash attention on matrix cores, TQ=64 TK=64,
//      fp32 online softmax in registers, P via LDS (wave-local strip),
//      writes fp16 attn matrix directly (out-proj A input)
//   5. gemm_bt_f16: out = attn @ wo^T + bo -> d_out fp32
//
// ws layout (bytes):
//   x_f16    :         0 .. 18874368
//   wqkv_f16 :  18874368 .. 23003136   (1792x1152; rows>=1728 poison, discarded)
//   wo_f16   :  23003136 .. 25657344
//   bias_qkv :  25657344 .. 25664256
//   qkv f32  :  25664256 .. 82287360   (8192x1728)
//   Qh       :  82287360 .. 103258880  (4,8,2048,160) f16
//   Kh       : 103258880 .. 108501760  (4,2,2048,160) f16
//   Vt       : 108501760 .. 113220352  (4,2,144,2048) f16
//   attn_f16 : 113220352 .. 132094720  (8192x1152) f16
// ============================================================================

#define THREADS 256

typedef _Float16 f16x8 __attribute__((ext_vector_type(8)));
typedef _Float16 f16x4 __attribute__((ext_vector_type(4)));
typedef _Float16 f16x2 __attribute__((ext_vector_type(2)));
typedef float f32x4 __attribute__((ext_vector_type(4)));

// ---------------------------------------------------------------- cvt fp32->fp16
__global__ __launch_bounds__(THREADS) void cvt_f16(const float* __restrict__ in,
                                                   _Float16* __restrict__ out,
                                                   int n4) {
  int i = blockIdx.x * THREADS + threadIdx.x;
  if (i >= n4) return;
  float4 v = ((const float4*)in)[i];
  f16x4 o;
  o.x = (_Float16)v.x;
  o.y = (_Float16)v.y;
  o.z = (_Float16)v.z;
  o.w = (_Float16)v.w;
  ((f16x4*)out)[i] = o;
}

// ---------------------------------------------------------------- bias concat
__global__ __launch_bounds__(THREADS) void prep_bias(const float* __restrict__ bq,
                                                     const float* __restrict__ bkv,
                                                     float* __restrict__ bias) {
  int i = blockIdx.x * THREADS + threadIdx.x;
  if (i < 1152) bias[i] = bq[i];
  else if (i < 1728) bias[i] = bkv[i - 1152];
}

// ---------------------------------------------------------------- GEMM-BT fp16 MFMA
// C[m,n] = sum_k A[m,k]*B[n,k] + bias[n]. 128x128 tile, BK=32, 4 waves.
// Verified layouts: A/B frag row=lane&15, k=quad*8+j; C/D col=lane&15, row=quad*4+reg.
__global__ __launch_bounds__(THREADS) void gemm_bt_f16(
    const _Float16* __restrict__ A, const _Float16* __restrict__ B,
    const float* __restrict__ bias, float* __restrict__ C, int M, int N, int K) {
  __shared__ __align__(16) _Float16 As[128 * 32];
  __shared__ __align__(16) _Float16 Bs[128 * 32];
  const int t = threadIdx.x;
  const int m0 = blockIdx.y << 7, n0 = blockIdx.x << 7;
  const int w = t >> 6, lane = t & 63;
  const int wm = (w & 1) << 6, wn = (w >> 1) << 6;
  const int quad = lane >> 4, l16 = lane & 15;

  f32x4 acc[4][4] = {};

  for (int k0 = 0; k0 < K; k0 += 32) {
#pragma unroll
    for (int i = 0; i < 2; ++i) {
      const int c = t + (i << 8);
      const int row = c >> 2, kc = (c & 3) << 3;
      float4 va = *(const float4*)(A + (size_t)(m0 + row) * K + (k0 + kc));
      float4 vb = *(const float4*)(B + (size_t)(n0 + row) * K + (k0 + kc));
      *(float4*)&As[c << 3] = va;
      *(float4*)&Bs[c << 3] = vb;
    }
    __syncthreads();
    f16x8 af[4], bf[4];
#pragma unroll
    for (int mi = 0; mi < 4; ++mi)
      af[mi] = *(const f16x8*)&As[((wm + (mi << 4) + l16) << 5) + (quad << 3)];
#pragma unroll
    for (int ni = 0; ni < 4; ++ni)
      bf[ni] = *(const f16x8*)&Bs[((wn + (ni << 4) + l16) << 5) + (quad << 3)];
#pragma unroll
    for (int mi = 0; mi < 4; ++mi)
#pragma unroll
      for (int ni = 0; ni < 4; ++ni)
        acc[mi][ni] =
            __builtin_amdgcn_mfma_f32_16x16x32_f16(af[mi], bf[ni], acc[mi][ni], 0, 0, 0);
    __syncthreads();
  }

#pragma unroll
  for (int mi = 0; mi < 4; ++mi) {
    const int row = m0 + wm + (mi << 4) + (quad << 2);
#pragma unroll
    for (int ni = 0; ni < 4; ++ni) {
      const int col = n0 + wn + (ni << 4) + l16;
      if (col < N) {
        const float bv = bias[col];
#pragma unroll
        for (int r = 0; r < 4; ++r)
          C[(size_t)(row + r) * N + col] = acc[mi][ni][r] + bv;
      }
    }
  }
}

// ---------------------------------------------------------------- RoPE -> fp16 Q/K
// qkv row (1728): [q 8x144 | k 2x144 | v 2x144]. Outputs padded d=160 (zeros).
// 800 jobs/row: 576 q-pairs, 144 k-pairs, 80 pad-pairs. Grid exact: 8192*800/256.
__global__ __launch_bounds__(THREADS) void rope_scatter_f16(
    const float* __restrict__ qkv, const float* __restrict__ fc,
    const float* __restrict__ fs, _Float16* __restrict__ Qh,
    _Float16* __restrict__ Kh) {
  int idx = blockIdx.x * THREADS + threadIdx.x;
  int m = idx / 800;
  int c = idx - m * 800;
  int s = m & 2047, b = m >> 11;
  const float* row = qkv + (size_t)m * 1728;
  if (c < 720) {
    int h, d2;
    const float* src;
    _Float16* dst;
    if (c < 576) {
      h = c / 72;
      d2 = c - h * 72;
      src = row + h * 144 + 2 * d2;
      dst = Qh + ((size_t)(b * 8 + h) * 2048 + s) * 160 + 2 * d2;
    } else {
      int cc = c - 576;
      h = cc / 72;
      d2 = cc - h * 72;
      src = row + 1152 + h * 144 + 2 * d2;
      dst = Kh + ((size_t)(b * 2 + h) * 2048 + s) * 160 + 2 * d2;
    }
    float2 v = *(const float2*)src;
    float cth = fc[s * 72 + d2], sth = fs[s * 72 + d2];
    f16x2 o;
    o.x = (_Float16)(v.x * cth - v.y * sth);
    o.y = (_Float16)(v.x * sth + v.y * cth);
    *(f16x2*)dst = o;
  } else {
    int pc = c - 720;  // 0..79 -> zero pads d=144..159
    _Float16* dst;
    if (pc < 64) {
      int h = pc >> 3, i = pc & 7;
      dst = Qh + ((size_t)(b * 8 + h) * 2048 + s) * 160 + 144 + 2 * i;
    } else {
      int p2 = pc - 64;
      int h = p2 >> 3, i = p2 & 7;
      dst = Kh + ((size_t)(b * 2 + h) * 2048 + s) * 160 + 144 + 2 * i;
    }
    f16x2 z;
    z.x = (_Float16)0.f;
    z.y = (_Float16)0.f;
    *(f16x2*)dst = z;
  }
}

// ---------------------------------------------------------------- V transpose
// qkv V cols -> Vt[b][kvh][d:144][s:2048] fp16. Block: (stile of 128 s, kvh, b).
__global__ __launch_bounds__(THREADS) void v_transpose(const float* __restrict__ qkv,
                                                       _Float16* __restrict__ Vt) {
  __shared__ _Float16 tile[128 * 145];  // stride 145: conflict-free strided reads
  const int t = threadIdx.x;
  const int s0 = blockIdx.x * 128;
  const int kvh = blockIdx.y, b = blockIdx.z;
  const float* src = qkv + ((size_t)(b * 2048 + s0)) * 1728 + 1440 + kvh * 144;
#pragma unroll
  for (int i = 0; i < 18; ++i) {
    int c = t + i * 256;  // 0..4607 = 128 rows x 36 float4
    int r = c / 36, cc = c - r * 36;
    float4 v = *(const float4*)(src + (size_t)r * 1728 + cc * 4);
    int base = r * 145 + cc * 4;
    tile[base + 0] = (_Float16)v.x;
    tile[base + 1] = (_Float16)v.y;
    tile[base + 2] = (_Float16)v.z;
    tile[base + 3] = (_Float16)v.w;
  }
  __syncthreads();
  _Float16* dstb = Vt + (size_t)(b * 2 + kvh) * 144 * 2048;
#pragma unroll
  for (int i = 0; i < 9; ++i) {
    int c = t + i * 256;  // 0..2303 = 144 d x 16 s-chunks
    int d = c >> 4, sc = c & 15;
    f16x8 o;
#pragma unroll
    for (int j = 0; j < 8; ++j) o[j] = tile[(sc * 8 + j) * 145 + d];
    *(f16x8*)(dstb + (size_t)d * 2048 + s0 + sc * 8) = o;
  }
}

// ---------------------------------------------------------------- MFMA flash attention
// Block (qt,h,b): 64 q-rows x key tiles of 64. Wave w owns q-rows w*16..+15.
// Q frags in registers (d padded to 160 -> 5 k-steps). K/Vt staged in LDS.
// Online softmax in registers (C-layout rows of QK == C-layout rows of PV).
// P -> LDS (wave-local 16-row strip) -> A-frags for PV. Output fp16.
__global__ __launch_bounds__(THREADS) void attn_mfma(
    const _Float16* __restrict__ Qh, const _Float16* __restrict__ Kh,
    const _Float16* __restrict__ Vt, _Float16* __restrict__ Out) {
  __shared__ __align__(16) _Float16 Ks[64 * 168];   // 64 keys x 160d, stride 168
  __shared__ __align__(16) _Float16 Vts[144 * 72];  // 144 d x 64 keys, stride 72
  __shared__ __align__(16) _Float16 Ps[64 * 72];    // 64 q x 64 keys, stride 72
  const int t = threadIdx.x;
  const int w = t >> 6, lane = t & 63;
  const int quad = lane >> 4, l16 = lane & 15;
  const int qt = (int)gridDim.x - 1 - (int)blockIdx.x;  // big blocks first
  const int h = blockIdx.y, b = blockIdx.z;
  const int kvh = h >> 2;
  const int qbase = qt * 64;
  const _Float16* Qg = Qh + ((size_t)(b * 8 + h) * 2048 + qbase) * 160;
  const _Float16* Kg = Kh + (size_t)(b * 2 + kvh) * 2048 * 160;
  const _Float16* Vg = Vt + (size_t)(b * 2 + kvh) * 144 * 2048;

  // Q fragments: rows w*16 + l16, k = ks*32 + quad*8 + j
  f16x8 qf[5];
#pragma unroll
  for (int ks = 0; ks < 5; ++ks)
    qf[ks] = *(const f16x8*)(Qg + (size_t)(w * 16 + l16) * 160 + ks * 32 + quad * 8);

  f32x4 Oacc[9] = {};
  float mrow[4] = {-INFINITY, -INFINITY, -INFINITY, -INFINITY};
  float lrow[4] = {0.f, 0.f, 0.f, 0.f};
  const float scale = 0.08333333333333333f;  // 1/sqrt(144)

  const int nkt = qt + 1;
  for (int kt = 0; kt < nkt; ++kt) {
    // ---- stage K tile (64x160, 1280 f16x8 chunks) and Vt tile (144x64, 1152)
#pragma unroll
    for (int i = 0; i < 5; ++i) {
      int c = t + (i << 8);
      int r = c / 20, cc = c - r * 20;
      *(float4*)&Ks[r * 168 + cc * 8] =
          *(const float4*)(Kg + (size_t)(kt * 64 + r) * 160 + cc * 8);
    }
    for (int c = t; c < 1152; c += THREADS) {
      int r = c >> 3, cc = c & 7;
      *(float4*)&Vts[r * 72 + cc * 8] =
          *(const float4*)(Vg + (size_t)r * 2048 + kt * 64 + cc * 8);
    }
    __syncthreads();

    // ---- QK^T: S strip = rows w*16..+15 x 64 keys (4 col-tiles)
    f32x4 s[4] = {};
#pragma unroll
    for (int ks = 0; ks < 5; ++ks) {
      f16x8 a = qf[ks];
#pragma unroll
      for (int ct = 0; ct < 4; ++ct) {
        f16x8 bf = *(const f16x8*)&Ks[(ct * 16 + l16) * 168 + ks * 32 + quad * 8];
        s[ct] = __builtin_amdgcn_mfma_f32_16x16x32_f16(a, bf, s[ct], 0, 0, 0);
      }
    }

    // ---- online softmax (rows: w*16 + quad*4 + r; cols: ct*16 + l16)
    float mx[4] = {-INFINITY, -INFINITY, -INFINITY, -INFINITY};
    const bool diag = (kt == qt);
#pragma unroll
    for (int ct = 0; ct < 4; ++ct)
#pragma unroll
      for (int r = 0; r < 4; ++r) {
        float v = s[ct][r] * scale;
        if (diag && (ct * 16 + l16) > (w * 16 + quad * 4 + r)) v -= 1e9f;
        s[ct][r] = v;
        mx[r] = fmaxf(mx[r], v);
      }
    float alv[4];
#pragma unroll
    for (int r = 0; r < 4; ++r) {
      float m = mx[r];
      m = fmaxf(m, __shfl_xor(m, 1));
      m = fmaxf(m, __shfl_xor(m, 2));
      m = fmaxf(m, __shfl_xor(m, 4));
      m = fmaxf(m, __shfl_xor(m, 8));
      float mn = fmaxf(mrow[r], m);
      alv[r] = __expf(mrow[r] - mn);
      mrow[r] = mn;
      lrow[r] *= alv[r];
    }
    float rs[4] = {0.f, 0.f, 0.f, 0.f};
#pragma unroll
    for (int ct = 0; ct < 4; ++ct)
#pragma unroll
      for (int r = 0; r < 4; ++r) {
        float p = __expf(s[ct][r] - mrow[r]);
        rs[r] += p;
        Ps[(w * 16 + quad * 4 + r) * 72 + ct * 16 + l16] = (_Float16)p;
      }
#pragma unroll
    for (int r = 0; r < 4; ++r) {
      float v = rs[r];
      v += __shfl_xor(v, 1);
      v += __shfl_xor(v, 2);
      v += __shfl_xor(v, 4);
      v += __shfl_xor(v, 8);
      lrow[r] += v;
    }
    // rescale O by alpha before adding this tile
#pragma unroll
    for (int nt = 0; nt < 9; ++nt)
#pragma unroll
      for (int r = 0; r < 4; ++r) Oacc[nt][r] *= alv[r];

    // ---- PV: O strip (16 x 144) += P(16x64) @ V(64x144); P strip is wave-local
#pragma unroll
    for (int ksv = 0; ksv < 2; ++ksv) {
      f16x8 pa = *(const f16x8*)&Ps[(w * 16 + l16) * 72 + ksv * 32 + quad * 8];
#pragma unroll
      for (int nt = 0; nt < 9; ++nt) {
        f16x8 vb = *(const f16x8*)&Vts[(nt * 16 + l16) * 72 + ksv * 32 + quad * 8];
        Oacc[nt] = __builtin_amdgcn_mfma_f32_16x16x32_f16(pa, vb, Oacc[nt], 0, 0, 0);
      }
    }
    __syncthreads();  // protect Ks/Vts before next staging
  }

  // ---- epilogue: out[b*2048+q][h*144 + d], fp16 (A-matrix of out-proj)
  float inv[4];
#pragma unroll
  for (int r = 0; r < 4; ++r) inv[r] = 1.f / lrow[r];
  _Float16* Og = Out + ((size_t)(b * 2048 + qbase + w * 16 + quad * 4)) * 1152 +
                 h * 144 + l16;
#pragma unroll
  for (int nt = 0; nt < 9; ++nt)
#pragma unroll
    for (int r = 0; r < 4; ++r)
      Og[(size_t)r * 1152 + nt * 16] = (_Float16)(Oacc[nt][r] * inv[r]);
}

// ============================================================================
extern "C" void kernel_launch(void* const* d_in, const int* in_sizes, int n_in,
                              void* d_out, int out_size, void* d_ws, size_t ws_size,
                              hipStream_t stream) {
  const float* x = (const float*)d_in[0];
  const float* wq = (const float*)d_in[1];
  const float* bq = (const float*)d_in[2];
  const float* wkv = (const float*)d_in[3];
  const float* bkv = (const float*)d_in[4];
  const float* wo = (const float*)d_in[5];
  const float* bo = (const float*)d_in[6];
  const float* fc = (const float*)d_in[7];
  const float* fs = (const float*)d_in[8];
  // d_in[9..12] (k_cache, v_cache, mask, start_pos) unused: start_pos=0 prefill.
  float* out = (float*)d_out;
  char* ws = (char*)d_ws;

  _Float16* x_f16 = (_Float16*)(ws + 0);
  _Float16* wqkv_f16 = (_Float16*)(ws + 18874368);
  _Float16* wo_f16 = (_Float16*)(ws + 23003136);
  float* bias_qkv = (float*)(ws + 25657344);
  float* qkv = (float*)(ws + 25664256);
  _Float16* Qh = (_Float16*)(ws + 82287360);
  _Float16* Kh = (_Float16*)(ws + 103258880);
  _Float16* Vt = (_Float16*)(ws + 108501760);
  _Float16* attn_f16 = (_Float16*)(ws + 113220352);

  cvt_f16<<<9216, THREADS, 0, stream>>>(x, x_f16, 2359296);
  cvt_f16<<<1296, THREADS, 0, stream>>>(wq, wqkv_f16, 331776);
  cvt_f16<<<648, THREADS, 0, stream>>>(wkv, wqkv_f16 + 1327104, 165888);
  cvt_f16<<<1296, THREADS, 0, stream>>>(wo, wo_f16, 331776);
  prep_bias<<<7, THREADS, 0, stream>>>(bq, bkv, bias_qkv);

  gemm_bt_f16<<<dim3(14, 64), THREADS, 0, stream>>>(x_f16, wqkv_f16, bias_qkv, qkv,
                                                    8192, 1728, 1152);

  rope_scatter_f16<<<25600, THREADS, 0, stream>>>(qkv, fc, fs, Qh, Kh);
  v_transpose<<<dim3(16, 2, 4), THREADS, 0, stream>>>(qkv, Vt);

  attn_mfma<<<dim3(32, 8, 4), THREADS, 0, stream>>>(Qh, Kh, Vt, attn_f16);

  gemm_bt_f16<<<dim3(9, 64), THREADS, 0, stream>>>(attn_f16, wo_f16, bo, out, 8192,
                                                   1152, 1152);
}